// Round 1
// baseline (514.933 us; speedup 1.0000x reference)
//
#include <hip/hip_runtime.h>
#include <hip/hip_bf16.h>

// VSSBlock: B=2 H=64 W=64 C=192 DM=384 N=16 R=12 K=4 L=4096
// Pipeline: LN -> in_proj GEMM -> dwconv3x3+SiLU -> x_proj (44-dim) per direction
//           -> segmented selective scan (3 passes) -> merge 4 dirs + outLN + silu(z) gate
//           -> out_proj GEMM + residual.

#define Lx 4096
#define DMc 384
#define Cc 192

// ---------------- LayerNorm (pre-norm, eps 1e-6), C=192, one wave per row ----------------
__global__ __launch_bounds__(256) void k_ln(const float* __restrict__ in,
                                            const float* __restrict__ g,
                                            const float* __restrict__ be,
                                            float* __restrict__ out) {
  int row = blockIdx.x * 4 + (threadIdx.x >> 6);
  int lane = threadIdx.x & 63;
  const float* x = in + (long)row * 192;
  float v0 = x[lane], v1 = x[lane + 64], v2 = x[lane + 128];
  float s = v0 + v1 + v2;
  float s2 = v0 * v0 + v1 * v1 + v2 * v2;
  #pragma unroll
  for (int o = 32; o > 0; o >>= 1) { s += __shfl_xor(s, o); s2 += __shfl_xor(s2, o); }
  float mu = s * (1.f / 192.f);
  float var = s2 * (1.f / 192.f) - mu * mu;
  float r = rsqrtf(var + 1e-6f);
  float* op = out + (long)row * 192;
  op[lane]       = (v0 - mu) * r * g[lane]       + be[lane];
  op[lane + 64]  = (v1 - mu) * r * g[lane + 64]  + be[lane + 64];
  op[lane + 128] = (v2 - mu) * r * g[lane + 128] + be[lane + 128];
}

// ---------------- fp32 tiled GEMM: C = A(MxK) * B(KxN) [+ Res], 64x64 tile, BK=32 ----------------
template <int RES>
__global__ __launch_bounds__(256) void k_gemm(const float* __restrict__ A,
                                              const float* __restrict__ Bw,
                                              const float* __restrict__ Res,
                                              float* __restrict__ Co,
                                              int M, int N, int Kk) {
  __shared__ float As[32][68];   // [k][m] transposed, rows 16B-aligned
  __shared__ float Bs2[32][68];  // [k][n]
  int row0 = blockIdx.y * 64, col0 = blockIdx.x * 64;
  int tid = threadIdx.x;
  int tx = tid & 15, ty = tid >> 4;
  float acc[4][4];
  #pragma unroll
  for (int i = 0; i < 4; i++)
    #pragma unroll
    for (int j = 0; j < 4; j++) acc[i][j] = 0.f;

  for (int k0 = 0; k0 < Kk; k0 += 32) {
    for (int i = tid; i < 2048; i += 256) {
      int m = i >> 5, kk = i & 31;
      As[kk][m] = A[(long)(row0 + m) * Kk + k0 + kk];
    }
    for (int i = tid; i < 2048; i += 256) {
      int kk = i >> 6, n = i & 63;
      Bs2[kk][n] = Bw[(long)(k0 + kk) * N + col0 + n];
    }
    __syncthreads();
    #pragma unroll
    for (int kk = 0; kk < 32; kk++) {
      float4 av = *(const float4*)&As[kk][ty * 4];
      float4 bv = *(const float4*)&Bs2[kk][tx * 4];
      acc[0][0] += av.x * bv.x; acc[0][1] += av.x * bv.y; acc[0][2] += av.x * bv.z; acc[0][3] += av.x * bv.w;
      acc[1][0] += av.y * bv.x; acc[1][1] += av.y * bv.y; acc[1][2] += av.y * bv.z; acc[1][3] += av.y * bv.w;
      acc[2][0] += av.z * bv.x; acc[2][1] += av.z * bv.y; acc[2][2] += av.z * bv.z; acc[2][3] += av.z * bv.w;
      acc[3][0] += av.w * bv.x; acc[3][1] += av.w * bv.y; acc[3][2] += av.w * bv.z; acc[3][3] += av.w * bv.w;
    }
    __syncthreads();
  }
  #pragma unroll
  for (int i = 0; i < 4; i++) {
    int rr = row0 + ty * 4 + i;
    #pragma unroll
    for (int j = 0; j < 4; j++) {
      int cc = col0 + tx * 4 + j;
      float v = acc[i][j];
      if (RES) v += Res[(long)rr * N + cc];
      Co[(long)rr * N + cc] = v;
    }
  }
}

// ---------------- depthwise 3x3 conv + bias + SiLU; x part = xz[:, 0:384] ----------------
__global__ __launch_bounds__(384) void k_conv(const float* __restrict__ xz,
                                              const float* __restrict__ cw,
                                              const float* __restrict__ cb,
                                              float* __restrict__ xc) {
  int row = blockIdx.x;  // b*4096 + p
  int b = row >> 12, p = row & 4095;
  int h = p >> 6, w0 = p & 63;
  int d = threadIdx.x;
  float acc = cb[d];
  const float* wt = cw + d * 9;
  #pragma unroll
  for (int dh = -1; dh <= 1; dh++) {
    int hh = h + dh;
    if (hh < 0 || hh > 63) continue;
    #pragma unroll
    for (int dw = -1; dw <= 1; dw++) {
      int ww = w0 + dw;
      if (ww < 0 || ww > 63) continue;
      acc += xz[((long)(b << 12) + (hh << 6) + ww) * 768 + d] * wt[(dh + 1) * 3 + (dw + 1)];
    }
  }
  float sg = 1.f / (1.f + __expf(-acc));
  xc[(long)row * 384 + d] = acc * sg;
}

// direction mapping: scan position l (direction k) -> pixel index p
__device__ __forceinline__ int dir_pix(int k, int l) {
  if (k == 0) return l;
  if (k == 1) return ((l & 63) << 6) | (l >> 6);
  if (k == 2) return 4095 - l;
  int l2 = 4095 - l;
  return ((l2 & 63) << 6) | (l2 >> 6);
}

// ---------------- x_proj: per (b,k,l) 44-dim = x_proj_w[k] @ u; split dts/Bs/Cs ----------------
__global__ __launch_bounds__(256) void k_xdbl(const float* __restrict__ xc,
                                              const float* __restrict__ xpw,
                                              float* __restrict__ dts,
                                              float* __restrict__ BsG,
                                              float* __restrict__ CsG) {
  int bid = blockIdx.x;          // ((b*4+k)*128 + lt)
  int lt = bid & 127;
  int bk = bid >> 7;
  int k = bk & 3, b = bk >> 2;
  int tid = threadIdx.x;
  __shared__ float u_s[32 * 385];  // 32 rows x 384, pad 1 (bank-friendly)
  int l0 = lt * 32;
  for (int i = tid; i < 32 * 384; i += 256) {
    int li = i / 384;
    int dd = i - li * 384;
    int p = dir_pix(k, l0 + li);
    u_s[li * 385 + dd] = xc[((long)(b << 12) + p) * 384 + dd];
  }
  __syncthreads();
  for (int idx = tid; idx < 44 * 32; idx += 256) {
    int c = idx >> 5, li = idx & 31;
    const float* w = xpw + ((long)(k * 44) + c) * 384;
    const float* u = u_s + li * 385;
    float acc = 0.f;
    #pragma unroll 4
    for (int r = 0; r < 384; r += 4) {
      float4 wv = *(const float4*)(w + r);
      acc += u[r] * wv.x + u[r + 1] * wv.y + u[r + 2] * wv.z + u[r + 3] * wv.w;
    }
    long lbase = (long)bk * 4096 + (l0 + li);
    if (c < 12)      dts[lbase * 12 + c] = acc;
    else if (c < 28) BsG[lbase * 16 + (c - 12)] = acc;
    else             CsG[lbase * 16 + (c - 28)] = acc;
  }
}

// ---------------- segmented selective scan; pass0: P,E per segment; pass1: emit y ----------------
// block = (b,k,seg), 64 segments of 64 steps; thread = channel d (384 threads)
__global__ __launch_bounds__(384) void k_scan(const float* __restrict__ dts,
                                              const float* __restrict__ xc,
                                              const float* __restrict__ BsG,
                                              const float* __restrict__ CsG,
                                              const float* __restrict__ A_logs,
                                              const float* __restrict__ dt_w,
                                              const float* __restrict__ dt_b,
                                              const float* __restrict__ Hin,
                                              float* __restrict__ P,
                                              float* __restrict__ E,
                                              float* __restrict__ Y,
                                              int pass) {
  int bid = blockIdx.x;  // ((b*4+k)*64 + s)
  int s = bid & 63;
  int bk = bid >> 6;
  int k = bk & 3, b = bk >> 2;
  int d = threadIdx.x;
  __shared__ float Bs_s[1024], Cs_s[1024], dt_s[768];
  {
    long b16 = ((long)bk * 4096 + s * 64) * 16;
    for (int i = d; i < 1024; i += 384) { Bs_s[i] = BsG[b16 + i]; Cs_s[i] = CsG[b16 + i]; }
    long b12 = ((long)bk * 4096 + s * 64) * 12;
    for (int i = d; i < 768; i += 384) dt_s[i] = dts[b12 + i];
  }
  float a[16], w[12];
  const float* al = A_logs + ((long)(k * 384) + d) * 16;
  #pragma unroll
  for (int n = 0; n < 16; n++) a[n] = -__expf(al[n]);
  const float* dwp = dt_w + ((long)(k * 384) + d) * 12;
  #pragma unroll
  for (int r = 0; r < 12; r++) w[r] = dwp[r];
  float db = dt_b[k * 384 + d];
  float h[16], Pr[16];
  if (pass == 0) {
    #pragma unroll
    for (int n = 0; n < 16; n++) h[n] = 0.f;
  } else {
    const float* hp = Hin + ((long)bk * 64 + s) * 6144 + d * 16;
    #pragma unroll
    for (int n = 0; n < 16; n++) h[n] = hp[n];
  }
  #pragma unroll
  for (int n = 0; n < 16; n++) Pr[n] = 1.f;
  __syncthreads();

  long baseY = ((long)bk * 4096 + s * 64) * 384 + d;
  long bxc = ((long)(b << 12)) * 384;
  for (int t = 0; t < 64; t++) {
    int l = s * 64 + t;
    float x = db;
    #pragma unroll
    for (int r = 0; r < 12; r++) x += dt_s[t * 12 + r] * w[r];
    float delta = (x > 15.f) ? x : __logf(1.f + __expf(x));  // softplus
    int p = dir_pix(k, l);
    float u = xc[bxc + (long)p * 384 + d];
    float du = delta * u;
    if (pass == 0) {
      #pragma unroll
      for (int n = 0; n < 16; n++) {
        float dA = __expf(delta * a[n]);
        h[n] = dA * h[n] + du * Bs_s[t * 16 + n];
        Pr[n] *= dA;
      }
    } else {
      float y = 0.f;
      #pragma unroll
      for (int n = 0; n < 16; n++) {
        float dA = __expf(delta * a[n]);
        h[n] = dA * h[n] + du * Bs_s[t * 16 + n];
        y += h[n] * Cs_s[t * 16 + n];
      }
      Y[baseY + t * 384] = y;
    }
  }
  if (pass == 0) {
    float* Pp = P + ((long)bk * 64 + s) * 6144 + d * 16;
    float* Ep = E + ((long)bk * 64 + s) * 6144 + d * 16;
    #pragma unroll
    for (int n = 0; n < 16; n++) { Pp[n] = Pr[n]; Ep[n] = h[n]; }
  }
}

// ---------------- cross-segment combine: h_in per segment ----------------
__global__ __launch_bounds__(256) void k_combine(const float* __restrict__ P,
                                                 const float* __restrict__ E,
                                                 float* __restrict__ Hin) {
  int t = blockIdx.x * 256 + threadIdx.x;  // over B*K*6144 = 49152
  int bk = t / 6144;
  int dn = t - bk * 6144;
  float h = 0.f;
  for (int s = 0; s < 64; s++) {
    long idx = ((long)bk * 64 + s) * 6144 + dn;
    Hin[idx] = h;
    h = P[idx] * h + E[idx];
  }
}

// ---------------- merge 4 directions + D-skip + out-LN (eps 1e-5) + silu(z) gate ----------------
__global__ __launch_bounds__(384) void k_merge(const float* __restrict__ Y,
                                               const float* __restrict__ xc,
                                               const float* __restrict__ xz,
                                               const float* __restrict__ Ds,
                                               const float* __restrict__ g,
                                               const float* __restrict__ be,
                                               float* __restrict__ yact) {
  int row = blockIdx.x;  // b*4096 + p
  int b = row >> 12, p = row & 4095;
  int d = threadIdx.x;
  int l1 = ((p & 63) << 6) | (p >> 6);
  long base = (long)b * 4 * 4096 * 384;
  float v = Y[base + ((long)0 * 4096 + p) * 384 + d]
          + Y[base + ((long)1 * 4096 + l1) * 384 + d]
          + Y[base + ((long)2 * 4096 + (4095 - p)) * 384 + d]
          + Y[base + ((long)3 * 4096 + (4095 - l1)) * 384 + d];
  float sd = Ds[d] + Ds[384 + d] + Ds[768 + d] + Ds[1152 + d];
  v += xc[(long)row * 384 + d] * sd;
  // block LN over 384
  float s1 = v, s2 = v * v;
  #pragma unroll
  for (int o = 32; o > 0; o >>= 1) { s1 += __shfl_xor(s1, o); s2 += __shfl_xor(s2, o); }
  __shared__ float r1[6], r2[6];
  int wv = threadIdx.x >> 6;
  if ((threadIdx.x & 63) == 0) { r1[wv] = s1; r2[wv] = s2; }
  __syncthreads();
  float S1 = 0.f, S2 = 0.f;
  #pragma unroll
  for (int i = 0; i < 6; i++) { S1 += r1[i]; S2 += r2[i]; }
  float mu = S1 * (1.f / 384.f);
  float var = S2 * (1.f / 384.f) - mu * mu;
  float rr = rsqrtf(var + 1e-5f);
  float yn = (v - mu) * rr * g[d] + be[d];
  float z = xz[(long)row * 768 + 384 + d];
  float sg = z / (1.f + __expf(-z));
  yact[(long)row * 384 + d] = yn * sg;
}

extern "C" void kernel_launch(void* const* d_in, const int* in_sizes, int n_in,
                              void* d_out, int out_size, void* d_ws, size_t ws_size,
                              hipStream_t stream) {
  const float* input      = (const float*)d_in[0];
  const float* norm_g     = (const float*)d_in[1];
  const float* norm_b     = (const float*)d_in[2];
  const float* in_proj_w  = (const float*)d_in[3];
  const float* conv_w     = (const float*)d_in[4];
  const float* conv_b     = (const float*)d_in[5];
  const float* x_proj_w   = (const float*)d_in[6];
  const float* dt_w       = (const float*)d_in[7];
  const float* dt_b       = (const float*)d_in[8];
  const float* A_logs     = (const float*)d_in[9];
  const float* Ds         = (const float*)d_in[10];
  const float* out_norm_g = (const float*)d_in[11];
  const float* out_norm_b = (const float*)d_in[12];
  const float* out_proj_w = (const float*)d_in[13];
  float* out = (float*)d_out;

  float* ws   = (float*)d_ws;
  float* xn   = ws;                  // 1,572,864  (B,L,C)
  float* xz   = xn + 1572864;        // 6,291,456  (B,L,768)
  float* xc   = xz + 6291456;        // 3,145,728  (B,L,DM)
  float* dts  = xc + 3145728;        //   393,216  (B,K,L,12)
  float* BsB  = dts + 393216;        //   524,288  (B,K,L,16)
  float* CsB  = BsB + 524288;        //   524,288
  float* Pb   = CsB + 524288;        // 3,145,728  (B,K,S,DM,16)
  float* Eb   = Pb + 3145728;        // 3,145,728
  float* Hb   = Eb + 3145728;        // 3,145,728
  float* Yb   = Hb + 3145728;        // 12,582,912 (B,K,L,DM)
  float* yact = Yb + 12582912;       // 3,145,728  (B,L,DM)
  // total: 37,617,664 floats = 150.5 MB

  k_ln<<<dim3(2048), dim3(256), 0, stream>>>(input, norm_g, norm_b, xn);
  k_gemm<0><<<dim3(12, 128), dim3(256), 0, stream>>>(xn, in_proj_w, nullptr, xz, 8192, 768, 192);
  k_conv<<<dim3(8192), dim3(384), 0, stream>>>(xz, conv_w, conv_b, xc);
  k_xdbl<<<dim3(1024), dim3(256), 0, stream>>>(xc, x_proj_w, dts, BsB, CsB);
  k_scan<<<dim3(512), dim3(384), 0, stream>>>(dts, xc, BsB, CsB, A_logs, dt_w, dt_b,
                                              nullptr, Pb, Eb, nullptr, 0);
  k_combine<<<dim3(192), dim3(256), 0, stream>>>(Pb, Eb, Hb);
  k_scan<<<dim3(512), dim3(384), 0, stream>>>(dts, xc, BsB, CsB, A_logs, dt_w, dt_b,
                                              Hb, nullptr, nullptr, Yb, 1);
  k_merge<<<dim3(8192), dim3(384), 0, stream>>>(Yb, xc, xz, Ds, out_norm_g, out_norm_b, yact);
  k_gemm<1><<<dim3(3, 128), dim3(256), 0, stream>>>(yact, out_proj_w, input, out, 8192, 192, 384);
}

// Round 2
// 470.190 us; speedup vs baseline: 1.0952x; 1.0952x over previous
//
#include <hip/hip_runtime.h>
#include <hip/hip_bf16.h>

// VSSBlock: B=2 H=64 W=64 C=192 DM=384 N=16 R=12 K=4 L=4096
// R2: x_proj computed pixel-major as one GEMM (xc @ W_all[384x192]); scan gathers
//     dts/Bs/Cs from the pixel-major xdbl buffer via dir_pix (same gather as xc).

// ---------------- LayerNorm (pre-norm, eps 1e-6), C=192, one wave per row ----------------
__global__ __launch_bounds__(256) void k_ln(const float* __restrict__ in,
                                            const float* __restrict__ g,
                                            const float* __restrict__ be,
                                            float* __restrict__ out) {
  int row = blockIdx.x * 4 + (threadIdx.x >> 6);
  int lane = threadIdx.x & 63;
  const float* x = in + (long)row * 192;
  float v0 = x[lane], v1 = x[lane + 64], v2 = x[lane + 128];
  float s = v0 + v1 + v2;
  float s2 = v0 * v0 + v1 * v1 + v2 * v2;
  #pragma unroll
  for (int o = 32; o > 0; o >>= 1) { s += __shfl_xor(s, o); s2 += __shfl_xor(s2, o); }
  float mu = s * (1.f / 192.f);
  float var = s2 * (1.f / 192.f) - mu * mu;
  float r = rsqrtf(var + 1e-6f);
  float* op = out + (long)row * 192;
  op[lane]       = (v0 - mu) * r * g[lane]       + be[lane];
  op[lane + 64]  = (v1 - mu) * r * g[lane + 64]  + be[lane + 64];
  op[lane + 128] = (v2 - mu) * r * g[lane + 128] + be[lane + 128];
}

// ---------------- fp32 tiled GEMM: C = A(MxK) * B(KxN) [+ Res], 64x64 tile, BK=32 ----------------
template <int RES>
__global__ __launch_bounds__(256) void k_gemm(const float* __restrict__ A,
                                              const float* __restrict__ Bw,
                                              const float* __restrict__ Res,
                                              float* __restrict__ Co,
                                              int M, int N, int Kk) {
  __shared__ float As[32][68];   // [k][m] transposed
  __shared__ float Bs2[32][68];  // [k][n]
  int row0 = blockIdx.y * 64, col0 = blockIdx.x * 64;
  int tid = threadIdx.x;
  int tx = tid & 15, ty = tid >> 4;
  float acc[4][4];
  #pragma unroll
  for (int i = 0; i < 4; i++)
    #pragma unroll
    for (int j = 0; j < 4; j++) acc[i][j] = 0.f;

  for (int k0 = 0; k0 < Kk; k0 += 32) {
    for (int i = tid; i < 2048; i += 256) {
      int m = i >> 5, kk = i & 31;
      As[kk][m] = A[(long)(row0 + m) * Kk + k0 + kk];
    }
    for (int i = tid; i < 2048; i += 256) {
      int kk = i >> 6, n = i & 63;
      Bs2[kk][n] = Bw[(long)(k0 + kk) * N + col0 + n];
    }
    __syncthreads();
    #pragma unroll
    for (int kk = 0; kk < 32; kk++) {
      float4 av = *(const float4*)&As[kk][ty * 4];
      float4 bv = *(const float4*)&Bs2[kk][tx * 4];
      acc[0][0] += av.x * bv.x; acc[0][1] += av.x * bv.y; acc[0][2] += av.x * bv.z; acc[0][3] += av.x * bv.w;
      acc[1][0] += av.y * bv.x; acc[1][1] += av.y * bv.y; acc[1][2] += av.y * bv.z; acc[1][3] += av.y * bv.w;
      acc[2][0] += av.z * bv.x; acc[2][1] += av.z * bv.y; acc[2][2] += av.z * bv.z; acc[2][3] += av.z * bv.w;
      acc[3][0] += av.w * bv.x; acc[3][1] += av.w * bv.y; acc[3][2] += av.w * bv.z; acc[3][3] += av.w * bv.w;
    }
    __syncthreads();
  }
  #pragma unroll
  for (int i = 0; i < 4; i++) {
    int rr = row0 + ty * 4 + i;
    int cc0 = col0 + tx * 4;
    float4 v4 = make_float4(acc[i][0], acc[i][1], acc[i][2], acc[i][3]);
    if (RES) {
      float4 r4 = *(const float4*)&Res[(long)rr * N + cc0];
      v4.x += r4.x; v4.y += r4.y; v4.z += r4.z; v4.w += r4.w;
    }
    *(float4*)&Co[(long)rr * N + cc0] = v4;
  }
}

// ---------------- depthwise 3x3 conv + bias + SiLU; x part = xz[:, 0:384] ----------------
__global__ __launch_bounds__(384) void k_conv(const float* __restrict__ xz,
                                              const float* __restrict__ cw,
                                              const float* __restrict__ cb,
                                              float* __restrict__ xc) {
  int row = blockIdx.x;  // b*4096 + p
  int b = row >> 12, p = row & 4095;
  int h = p >> 6, w0 = p & 63;
  int d = threadIdx.x;
  float acc = cb[d];
  const float* wt = cw + d * 9;
  #pragma unroll
  for (int dh = -1; dh <= 1; dh++) {
    int hh = h + dh;
    if (hh < 0 || hh > 63) continue;
    #pragma unroll
    for (int dw = -1; dw <= 1; dw++) {
      int ww = w0 + dw;
      if (ww < 0 || ww > 63) continue;
      acc += xz[((long)(b << 12) + (hh << 6) + ww) * 768 + d] * wt[(dh + 1) * 3 + (dw + 1)];
    }
  }
  float sg = 1.f / (1.f + __expf(-acc));
  xc[(long)row * 384 + d] = acc * sg;
}

// direction mapping: scan position l (direction k) -> pixel index p
__device__ __forceinline__ int dir_pix(int k, int l) {
  if (k == 0) return l;
  if (k == 1) return ((l & 63) << 6) | (l >> 6);
  if (k == 2) return 4095 - l;
  int l2 = 4095 - l;
  return ((l2 & 63) << 6) | (l2 >> 6);
}

// ---------------- pack x_proj_w (4,44,384) -> W_all (384 x 192), cols j=k*44+c, pad 176..191=0 ----------------
__global__ __launch_bounds__(256) void k_wpack(const float* __restrict__ xpw,
                                               float* __restrict__ W_all) {
  int idx = blockIdx.x * 256 + threadIdx.x;  // 384*192 = 73728
  if (idx >= 384 * 192) return;
  int dcol = idx / 192;
  int j = idx - dcol * 192;
  float v = 0.f;
  if (j < 176) {
    int k = j / 44, c = j - k * 44;
    v = xpw[((long)(k * 44) + c) * 384 + dcol];
  }
  W_all[idx] = v;
}

// ---------------- segmented selective scan; pass0: P,E per segment; pass1: emit y ----------------
// block = (b,k,seg), 64 segments of 64 steps; thread = channel d (384 threads)
// dts/Bs/Cs come from the pixel-major xdbl buffer: xdbl[(b*4096+p)*192 + k*44 + {0..11|12..27|28..43}]
__global__ __launch_bounds__(384) void k_scan(const float* __restrict__ xdbl,
                                              const float* __restrict__ xc,
                                              const float* __restrict__ A_logs,
                                              const float* __restrict__ dt_w,
                                              const float* __restrict__ dt_b,
                                              const float* __restrict__ Hin,
                                              float* __restrict__ P,
                                              float* __restrict__ E,
                                              float* __restrict__ Y,
                                              int pass) {
  int bid = blockIdx.x;  // ((b*4+k)*64 + s)
  int s = bid & 63;
  int bk = bid >> 6;
  int k = bk & 3, b = bk >> 2;
  int d = threadIdx.x;
  __shared__ float Bs_s[1024], Cs_s[1024], dt_s[768];
  {
    int l0 = s * 64;
    int kc = k * 44;
    long bpix = (long)(b << 12);
    for (int i = d; i < 64 * 44; i += 384) {
      int t = i / 44, c = i - t * 44;
      int p = dir_pix(k, l0 + t);
      float v = xdbl[(bpix + p) * 192 + kc + c];
      if (c < 12)      dt_s[t * 12 + c] = v;
      else if (c < 28) Bs_s[t * 16 + (c - 12)] = v;
      else             Cs_s[t * 16 + (c - 28)] = v;
    }
  }
  float a[16], w[12];
  const float* al = A_logs + ((long)(k * 384) + d) * 16;
  #pragma unroll
  for (int n = 0; n < 16; n++) a[n] = -__expf(al[n]);
  const float* dwp = dt_w + ((long)(k * 384) + d) * 12;
  #pragma unroll
  for (int r = 0; r < 12; r++) w[r] = dwp[r];
  float db = dt_b[k * 384 + d];
  float h[16], Pr[16];
  if (pass == 0) {
    #pragma unroll
    for (int n = 0; n < 16; n++) h[n] = 0.f;
  } else {
    const float* hp = Hin + ((long)bk * 64 + s) * 6144 + d * 16;
    #pragma unroll
    for (int n = 0; n < 16; n++) h[n] = hp[n];
  }
  #pragma unroll
  for (int n = 0; n < 16; n++) Pr[n] = 1.f;
  __syncthreads();

  long baseY = ((long)bk * 4096 + s * 64) * 384 + d;
  long bxc = ((long)(b << 12)) * 384;
  for (int t = 0; t < 64; t++) {
    int l = s * 64 + t;
    float x = db;
    #pragma unroll
    for (int r = 0; r < 12; r++) x += dt_s[t * 12 + r] * w[r];
    float delta = (x > 15.f) ? x : __logf(1.f + __expf(x));  // softplus
    int p = dir_pix(k, l);
    float u = xc[bxc + (long)p * 384 + d];
    float du = delta * u;
    if (pass == 0) {
      #pragma unroll
      for (int n = 0; n < 16; n++) {
        float dA = __expf(delta * a[n]);
        h[n] = dA * h[n] + du * Bs_s[t * 16 + n];
        Pr[n] *= dA;
      }
    } else {
      float y = 0.f;
      #pragma unroll
      for (int n = 0; n < 16; n++) {
        float dA = __expf(delta * a[n]);
        h[n] = dA * h[n] + du * Bs_s[t * 16 + n];
        y += h[n] * Cs_s[t * 16 + n];
      }
      Y[baseY + t * 384] = y;
    }
  }
  if (pass == 0) {
    float* Pp = P + ((long)bk * 64 + s) * 6144 + d * 16;
    float* Ep = E + ((long)bk * 64 + s) * 6144 + d * 16;
    #pragma unroll
    for (int n = 0; n < 16; n++) { Pp[n] = Pr[n]; Ep[n] = h[n]; }
  }
}

// ---------------- cross-segment combine: h_in per segment ----------------
__global__ __launch_bounds__(256) void k_combine(const float* __restrict__ P,
                                                 const float* __restrict__ E,
                                                 float* __restrict__ Hin) {
  int t = blockIdx.x * 256 + threadIdx.x;  // over B*K*6144 = 49152
  int bk = t / 6144;
  int dn = t - bk * 6144;
  float h = 0.f;
  for (int s = 0; s < 64; s++) {
    long idx = ((long)bk * 64 + s) * 6144 + dn;
    Hin[idx] = h;
    h = P[idx] * h + E[idx];
  }
}

// ---------------- merge 4 directions + D-skip + out-LN (eps 1e-5) + silu(z) gate ----------------
__global__ __launch_bounds__(384) void k_merge(const float* __restrict__ Y,
                                               const float* __restrict__ xc,
                                               const float* __restrict__ xz,
                                               const float* __restrict__ Ds,
                                               const float* __restrict__ g,
                                               const float* __restrict__ be,
                                               float* __restrict__ yact) {
  int row = blockIdx.x;  // b*4096 + p
  int b = row >> 12, p = row & 4095;
  int d = threadIdx.x;
  int l1 = ((p & 63) << 6) | (p >> 6);
  long base = (long)b * 4 * 4096 * 384;
  float v = Y[base + ((long)0 * 4096 + p) * 384 + d]
          + Y[base + ((long)1 * 4096 + l1) * 384 + d]
          + Y[base + ((long)2 * 4096 + (4095 - p)) * 384 + d]
          + Y[base + ((long)3 * 4096 + (4095 - l1)) * 384 + d];
  float sd = Ds[d] + Ds[384 + d] + Ds[768 + d] + Ds[1152 + d];
  v += xc[(long)row * 384 + d] * sd;
  float s1 = v, s2 = v * v;
  #pragma unroll
  for (int o = 32; o > 0; o >>= 1) { s1 += __shfl_xor(s1, o); s2 += __shfl_xor(s2, o); }
  __shared__ float r1[6], r2[6];
  int wv = threadIdx.x >> 6;
  if ((threadIdx.x & 63) == 0) { r1[wv] = s1; r2[wv] = s2; }
  __syncthreads();
  float S1 = 0.f, S2 = 0.f;
  #pragma unroll
  for (int i = 0; i < 6; i++) { S1 += r1[i]; S2 += r2[i]; }
  float mu = S1 * (1.f / 384.f);
  float var = S2 * (1.f / 384.f) - mu * mu;
  float rr = rsqrtf(var + 1e-5f);
  float yn = (v - mu) * rr * g[d] + be[d];
  float z = xz[(long)row * 768 + 384 + d];
  float sg = z / (1.f + __expf(-z));
  yact[(long)row * 384 + d] = yn * sg;
}

extern "C" void kernel_launch(void* const* d_in, const int* in_sizes, int n_in,
                              void* d_out, int out_size, void* d_ws, size_t ws_size,
                              hipStream_t stream) {
  const float* input      = (const float*)d_in[0];
  const float* norm_g     = (const float*)d_in[1];
  const float* norm_b     = (const float*)d_in[2];
  const float* in_proj_w  = (const float*)d_in[3];
  const float* conv_w     = (const float*)d_in[4];
  const float* conv_b     = (const float*)d_in[5];
  const float* x_proj_w   = (const float*)d_in[6];
  const float* dt_w       = (const float*)d_in[7];
  const float* dt_b       = (const float*)d_in[8];
  const float* A_logs     = (const float*)d_in[9];
  const float* Ds         = (const float*)d_in[10];
  const float* out_norm_g = (const float*)d_in[11];
  const float* out_norm_b = (const float*)d_in[12];
  const float* out_proj_w = (const float*)d_in[13];
  float* out = (float*)d_out;

  float* ws    = (float*)d_ws;
  float* xn    = ws;                  // 1,572,864  (B,L,C)
  float* xz    = xn + 1572864;        // 6,291,456  (B,L,768)
  float* xc    = xz + 6291456;        // 3,145,728  (B,L,DM)
  float* W_all = xc + 3145728;        //    73,728  (384,192)
  float* xdbl  = W_all + 73728;       // 1,572,864  (B,L,192)
  float* Pb    = xdbl + 1572864;      // 3,145,728  (B,K,S,DM,16)
  float* Eb    = Pb + 3145728;        // 3,145,728
  float* Hb    = Eb + 3145728;        // 3,145,728
  float* Yb    = Hb + 3145728;        // 12,582,912 (B,K,L,DM)
  float* yact  = Yb + 12582912;       // 3,145,728  (B,L,DM)
  // total: 37,822,464 floats ≈ 151.3 MB

  k_ln<<<dim3(2048), dim3(256), 0, stream>>>(input, norm_g, norm_b, xn);
  k_gemm<0><<<dim3(12, 128), dim3(256), 0, stream>>>(xn, in_proj_w, nullptr, xz, 8192, 768, 192);
  k_conv<<<dim3(8192), dim3(384), 0, stream>>>(xz, conv_w, conv_b, xc);
  k_wpack<<<dim3(288), dim3(256), 0, stream>>>(x_proj_w, W_all);
  k_gemm<0><<<dim3(3, 128), dim3(256), 0, stream>>>(xc, W_all, nullptr, xdbl, 8192, 192, 384);
  k_scan<<<dim3(512), dim3(384), 0, stream>>>(xdbl, xc, A_logs, dt_w, dt_b,
                                              nullptr, Pb, Eb, nullptr, 0);
  k_combine<<<dim3(192), dim3(256), 0, stream>>>(Pb, Eb, Hb);
  k_scan<<<dim3(512), dim3(384), 0, stream>>>(xdbl, xc, A_logs, dt_w, dt_b,
                                              Hb, nullptr, nullptr, Yb, 1);
  k_merge<<<dim3(8192), dim3(384), 0, stream>>>(Yb, xc, xz, Ds, out_norm_g, out_norm_b, yact);
  k_gemm<1><<<dim3(3, 128), dim3(256), 0, stream>>>(yact, out_proj_w, input, out, 8192, 192, 384);
}

// Round 3
// 425.385 us; speedup vs baseline: 1.2105x; 1.1053x over previous
//
#include <hip/hip_runtime.h>
#include <hip/hip_bf16.h>

// VSSBlock: B=2 H=64 W=64 C=192 DM=384 N=16 R=12 K=4 L=4096
// R3: scan restructured — scan-order dts/Bs/Cs buffers read via wave-uniform
//     scalar loads (no LDS), power-trick for dA (A_logs = log(1..16) => dA_n = r^(n+1),
//     with generic fallback), S=128 segments, pass1 atomicAdds into a single
//     (B,L,DM) y-accumulator (no 50MB Yb).

// ---------------- LayerNorm (pre-norm, eps 1e-6), C=192, one wave per row ----------------
__global__ __launch_bounds__(256) void k_ln(const float* __restrict__ in,
                                            const float* __restrict__ g,
                                            const float* __restrict__ be,
                                            float* __restrict__ out) {
  int row = blockIdx.x * 4 + (threadIdx.x >> 6);
  int lane = threadIdx.x & 63;
  const float* x = in + (long)row * 192;
  float v0 = x[lane], v1 = x[lane + 64], v2 = x[lane + 128];
  float s = v0 + v1 + v2;
  float s2 = v0 * v0 + v1 * v1 + v2 * v2;
  #pragma unroll
  for (int o = 32; o > 0; o >>= 1) { s += __shfl_xor(s, o); s2 += __shfl_xor(s2, o); }
  float mu = s * (1.f / 192.f);
  float var = s2 * (1.f / 192.f) - mu * mu;
  float r = rsqrtf(var + 1e-6f);
  float* op = out + (long)row * 192;
  op[lane]       = (v0 - mu) * r * g[lane]       + be[lane];
  op[lane + 64]  = (v1 - mu) * r * g[lane + 64]  + be[lane + 64];
  op[lane + 128] = (v2 - mu) * r * g[lane + 128] + be[lane + 128];
}

// ---------------- fp32 tiled GEMM: C = A(MxK) * B(KxN) [+ Res], 64x64 tile, BK=32 ----------------
template <int RES>
__global__ __launch_bounds__(256) void k_gemm(const float* __restrict__ A,
                                              const float* __restrict__ Bw,
                                              const float* __restrict__ Res,
                                              float* __restrict__ Co,
                                              int M, int N, int Kk) {
  __shared__ float As[32][68];   // [k][m] transposed
  __shared__ float Bs2[32][68];  // [k][n]
  int row0 = blockIdx.y * 64, col0 = blockIdx.x * 64;
  int tid = threadIdx.x;
  int tx = tid & 15, ty = tid >> 4;
  float acc[4][4];
  #pragma unroll
  for (int i = 0; i < 4; i++)
    #pragma unroll
    for (int j = 0; j < 4; j++) acc[i][j] = 0.f;

  for (int k0 = 0; k0 < Kk; k0 += 32) {
    for (int i = tid; i < 2048; i += 256) {
      int m = i >> 5, kk = i & 31;
      As[kk][m] = A[(long)(row0 + m) * Kk + k0 + kk];
    }
    for (int i = tid; i < 2048; i += 256) {
      int kk = i >> 6, n = i & 63;
      Bs2[kk][n] = Bw[(long)(k0 + kk) * N + col0 + n];
    }
    __syncthreads();
    #pragma unroll
    for (int kk = 0; kk < 32; kk++) {
      float4 av = *(const float4*)&As[kk][ty * 4];
      float4 bv = *(const float4*)&Bs2[kk][tx * 4];
      acc[0][0] += av.x * bv.x; acc[0][1] += av.x * bv.y; acc[0][2] += av.x * bv.z; acc[0][3] += av.x * bv.w;
      acc[1][0] += av.y * bv.x; acc[1][1] += av.y * bv.y; acc[1][2] += av.y * bv.z; acc[1][3] += av.y * bv.w;
      acc[2][0] += av.z * bv.x; acc[2][1] += av.z * bv.y; acc[2][2] += av.z * bv.z; acc[2][3] += av.z * bv.w;
      acc[3][0] += av.w * bv.x; acc[3][1] += av.w * bv.y; acc[3][2] += av.w * bv.z; acc[3][3] += av.w * bv.w;
    }
    __syncthreads();
  }
  #pragma unroll
  for (int i = 0; i < 4; i++) {
    int rr = row0 + ty * 4 + i;
    int cc0 = col0 + tx * 4;
    float4 v4 = make_float4(acc[i][0], acc[i][1], acc[i][2], acc[i][3]);
    if (RES) {
      float4 r4 = *(const float4*)&Res[(long)rr * N + cc0];
      v4.x += r4.x; v4.y += r4.y; v4.z += r4.z; v4.w += r4.w;
    }
    *(float4*)&Co[(long)rr * N + cc0] = v4;
  }
}

// ---------------- depthwise 3x3 conv + bias + SiLU; x part = xz[:, 0:384] ----------------
__global__ __launch_bounds__(384) void k_conv(const float* __restrict__ xz,
                                              const float* __restrict__ cw,
                                              const float* __restrict__ cb,
                                              float* __restrict__ xc) {
  int row = blockIdx.x;  // b*4096 + p
  int b = row >> 12, p = row & 4095;
  int h = p >> 6, w0 = p & 63;
  int d = threadIdx.x;
  float acc = cb[d];
  const float* wt = cw + d * 9;
  #pragma unroll
  for (int dh = -1; dh <= 1; dh++) {
    int hh = h + dh;
    if (hh < 0 || hh > 63) continue;
    #pragma unroll
    for (int dw = -1; dw <= 1; dw++) {
      int ww = w0 + dw;
      if (ww < 0 || ww > 63) continue;
      acc += xz[((long)(b << 12) + (hh << 6) + ww) * 768 + d] * wt[(dh + 1) * 3 + (dw + 1)];
    }
  }
  float sg = 1.f / (1.f + __expf(-acc));
  xc[(long)row * 384 + d] = acc * sg;
}

// direction mapping: scan position l (direction k) -> pixel index p
__device__ __forceinline__ int dir_pix(int k, int l) {
  if (k == 0) return l;
  if (k == 1) return ((l & 63) << 6) | (l >> 6);
  if (k == 2) return 4095 - l;
  int l2 = 4095 - l;
  return ((l2 & 63) << 6) | (l2 >> 6);
}

// ---------------- pack x_proj_w (4,44,384) -> W_all (384 x 192), cols j=k*44+c, pad 176..191=0 ----------------
__global__ __launch_bounds__(256) void k_wpack(const float* __restrict__ xpw,
                                               float* __restrict__ W_all) {
  int idx = blockIdx.x * 256 + threadIdx.x;  // 384*192 = 73728
  if (idx >= 384 * 192) return;
  int dcol = idx / 192;
  int j = idx - dcol * 192;
  float v = 0.f;
  if (j < 176) {
    int k = j / 44, c = j - k * 44;
    v = xpw[((long)(k * 44) + c) * 384 + dcol];
  }
  W_all[idx] = v;
}

// ---------------- repack pixel-major xdbl -> scan-ordered dts/Bs/Cs ----------------
__global__ __launch_bounds__(256) void k_repack(const float* __restrict__ xdbl,
                                                float* __restrict__ dtsS,
                                                float* __restrict__ BsS,
                                                float* __restrict__ CsS) {
  int bid = blockIdx.x;  // bk*64 + lt  (8*64 = 512)
  int lt = bid & 63, bk = bid >> 6;
  int k = bk & 3, b = bk >> 2;
  int l0 = lt * 64;
  long bpix = (long)(b << 12);
  int kc = k * 44;
  for (int i = threadIdx.x; i < 64 * 44; i += 256) {
    int t = i / 44, c = i - t * 44;
    int p = dir_pix(k, l0 + t);
    float v = xdbl[(bpix + p) * 192 + kc + c];
    long lbase = (long)bk * 4096 + l0 + t;
    if (c < 12)      dtsS[lbase * 12 + c] = v;
    else if (c < 28) BsS[lbase * 16 + (c - 12)] = v;
    else             CsS[lbase * 16 + (c - 28)] = v;
  }
}

// ---------------- segmented selective scan: 128 segments x 32 steps ----------------
// block = (bk, seg); thread = channel d. dts/Bs/Cs read at wave-uniform addresses
// (scalar loads). PASS 0: publish per-segment decay product P and endpoint E.
// PASS 1: start from Hin, atomicAdd y into ysum (pixel-major accumulator).
template <int PASS>
__global__ __launch_bounds__(384) void k_scan(
    const float* __restrict__ dtsS, const float* __restrict__ BsS,
    const float* __restrict__ CsS, const float* __restrict__ xc,
    const float* __restrict__ A_logs, const float* __restrict__ dt_w,
    const float* __restrict__ dt_b, const float* __restrict__ Hin,
    float* __restrict__ P, float* __restrict__ E, float* __restrict__ ysum) {
  int bid = blockIdx.x;
  int s = bid & 127, bk = bid >> 7;
  int k = bk & 3, b = bk >> 2;
  int d = threadIdx.x;
  float w[12];
  const float* dwp = dt_w + ((long)(k * 384) + d) * 12;
  #pragma unroll
  for (int r = 0; r < 12; r++) w[r] = dwp[r];
  float db = dt_b[k * 384 + d];
  const float* al = A_logs + ((long)(k * 384) + d) * 16;
  bool pw = true;
  #pragma unroll
  for (int n = 0; n < 16; n++) {
    float a = __expf(al[n]);
    pw = pw && (fabsf(a - (float)(n + 1)) < 1e-3f);
  }
  float h[16];
  if (PASS == 0) {
    #pragma unroll
    for (int n = 0; n < 16; n++) h[n] = 0.f;
  } else {
    const float* hp = Hin + ((long)bk * 128 + s) * 6144 + d * 16;
    #pragma unroll
    for (int n = 0; n < 16; n++) h[n] = hp[n];
  }
  long lb = (long)bk * 4096 + s * 32;
  long bpix = (long)(b << 12);
  float rprod = 1.f;
  float PrG[16];
  #pragma unroll
  for (int n = 0; n < 16; n++) PrG[n] = 1.f;

  if (pw) {
    // dA_n = exp(-delta*(n+1)) = r^(n+1), r = exp(-delta)
    #pragma unroll 4
    for (int t = 0; t < 32; t++) {
      int l = s * 32 + t;
      const float4* dq = (const float4*)(dtsS + (lb + t) * 12);
      float4 q0 = dq[0], q1 = dq[1], q2 = dq[2];
      float x = db + q0.x * w[0] + q0.y * w[1] + q0.z * w[2] + q0.w * w[3]
                   + q1.x * w[4] + q1.y * w[5] + q1.z * w[6] + q1.w * w[7]
                   + q2.x * w[8] + q2.y * w[9] + q2.z * w[10] + q2.w * w[11];
      float delta = (x > 15.f) ? x : __logf(1.f + __expf(x));
      int p = dir_pix(k, l);
      float u = xc[(bpix + p) * 384 + d];
      float du = delta * u;
      float rr = __expf(-delta);
      const float4* Bq = (const float4*)(BsS + (lb + t) * 16);
      float4 b0 = Bq[0], b1 = Bq[1], b2 = Bq[2], b3 = Bq[3];
      float Bl[16] = {b0.x, b0.y, b0.z, b0.w, b1.x, b1.y, b1.z, b1.w,
                      b2.x, b2.y, b2.z, b2.w, b3.x, b3.y, b3.z, b3.w};
      float rp = rr;
      if (PASS == 0) {
        #pragma unroll
        for (int n = 0; n < 16; n++) { h[n] = rp * h[n] + du * Bl[n]; rp *= rr; }
        rprod *= rr;
      } else {
        const float4* Cq = (const float4*)(CsS + (lb + t) * 16);
        float4 c0 = Cq[0], c1 = Cq[1], c2 = Cq[2], c3 = Cq[3];
        float Cl[16] = {c0.x, c0.y, c0.z, c0.w, c1.x, c1.y, c1.z, c1.w,
                        c2.x, c2.y, c2.z, c2.w, c3.x, c3.y, c3.z, c3.w};
        float y = 0.f;
        #pragma unroll
        for (int n = 0; n < 16; n++) {
          h[n] = rp * h[n] + du * Bl[n];
          y += h[n] * Cl[n];
          rp *= rr;
        }
        atomicAdd(&ysum[(bpix + p) * 384 + d], y);
      }
    }
  } else {
    // generic fallback: dA_n = exp(delta * a_n)
    float av[16];
    #pragma unroll
    for (int n = 0; n < 16; n++) av[n] = -__expf(al[n]);
    for (int t = 0; t < 32; t++) {
      int l = s * 32 + t;
      const float4* dq = (const float4*)(dtsS + (lb + t) * 12);
      float4 q0 = dq[0], q1 = dq[1], q2 = dq[2];
      float x = db + q0.x * w[0] + q0.y * w[1] + q0.z * w[2] + q0.w * w[3]
                   + q1.x * w[4] + q1.y * w[5] + q1.z * w[6] + q1.w * w[7]
                   + q2.x * w[8] + q2.y * w[9] + q2.z * w[10] + q2.w * w[11];
      float delta = (x > 15.f) ? x : __logf(1.f + __expf(x));
      int p = dir_pix(k, l);
      float u = xc[(bpix + p) * 384 + d];
      float du = delta * u;
      const float4* Bq = (const float4*)(BsS + (lb + t) * 16);
      float4 b0 = Bq[0], b1 = Bq[1], b2 = Bq[2], b3 = Bq[3];
      float Bl[16] = {b0.x, b0.y, b0.z, b0.w, b1.x, b1.y, b1.z, b1.w,
                      b2.x, b2.y, b2.z, b2.w, b3.x, b3.y, b3.z, b3.w};
      if (PASS == 0) {
        #pragma unroll
        for (int n = 0; n < 16; n++) {
          float dA = __expf(delta * av[n]);
          h[n] = dA * h[n] + du * Bl[n];
          PrG[n] *= dA;
        }
      } else {
        const float4* Cq = (const float4*)(CsS + (lb + t) * 16);
        float4 c0 = Cq[0], c1 = Cq[1], c2 = Cq[2], c3 = Cq[3];
        float Cl[16] = {c0.x, c0.y, c0.z, c0.w, c1.x, c1.y, c1.z, c1.w,
                        c2.x, c2.y, c2.z, c2.w, c3.x, c3.y, c3.z, c3.w};
        float y = 0.f;
        #pragma unroll
        for (int n = 0; n < 16; n++) {
          float dA = __expf(delta * av[n]);
          h[n] = dA * h[n] + du * Bl[n];
          y += h[n] * Cl[n];
        }
        atomicAdd(&ysum[(bpix + p) * 384 + d], y);
      }
    }
  }
  if (PASS == 0) {
    float* Pp = P + ((long)bk * 128 + s) * 6144 + d * 16;
    float* Ep = E + ((long)bk * 128 + s) * 6144 + d * 16;
    if (pw) {
      float pp = rprod;
      #pragma unroll
      for (int n = 0; n < 16; n++) { Pp[n] = pp; Ep[n] = h[n]; pp *= rprod; }
    } else {
      #pragma unroll
      for (int n = 0; n < 16; n++) { Pp[n] = PrG[n]; Ep[n] = h[n]; }
    }
  }
}

// ---------------- cross-segment combine: h_in per segment (serial over 128 segs) ----------------
__global__ __launch_bounds__(256) void k_combine(const float* __restrict__ P,
                                                 const float* __restrict__ E,
                                                 float* __restrict__ Hin) {
  int t = blockIdx.x * 256 + threadIdx.x;  // over B*K*6144 = 49152
  int bk = t / 6144;
  int dn = t - bk * 6144;
  long base = (long)bk * 128 * 6144 + dn;
  float h = 0.f;
  for (int s = 0; s < 128; s++) {
    long idx = base + (long)s * 6144;
    Hin[idx] = h;
    h = P[idx] * h + E[idx];
  }
}

// ---------------- merge: ysum + D-skip + out-LN (eps 1e-5) + silu(z) gate ----------------
__global__ __launch_bounds__(384) void k_merge(const float* __restrict__ ysum,
                                               const float* __restrict__ xc,
                                               const float* __restrict__ xz,
                                               const float* __restrict__ Ds,
                                               const float* __restrict__ g,
                                               const float* __restrict__ be,
                                               float* __restrict__ yact) {
  int row = blockIdx.x;  // b*4096 + p
  int d = threadIdx.x;
  float v = ysum[(long)row * 384 + d];
  float sd = Ds[d] + Ds[384 + d] + Ds[768 + d] + Ds[1152 + d];
  v += xc[(long)row * 384 + d] * sd;
  float s1 = v, s2 = v * v;
  #pragma unroll
  for (int o = 32; o > 0; o >>= 1) { s1 += __shfl_xor(s1, o); s2 += __shfl_xor(s2, o); }
  __shared__ float r1[6], r2[6];
  int wv = threadIdx.x >> 6;
  if ((threadIdx.x & 63) == 0) { r1[wv] = s1; r2[wv] = s2; }
  __syncthreads();
  float S1 = 0.f, S2 = 0.f;
  #pragma unroll
  for (int i = 0; i < 6; i++) { S1 += r1[i]; S2 += r2[i]; }
  float mu = S1 * (1.f / 384.f);
  float var = S2 * (1.f / 384.f) - mu * mu;
  float rr = rsqrtf(var + 1e-5f);
  float yn = (v - mu) * rr * g[d] + be[d];
  float z = xz[(long)row * 768 + 384 + d];
  float sg = z / (1.f + __expf(-z));
  yact[(long)row * 384 + d] = yn * sg;
}

extern "C" void kernel_launch(void* const* d_in, const int* in_sizes, int n_in,
                              void* d_out, int out_size, void* d_ws, size_t ws_size,
                              hipStream_t stream) {
  const float* input      = (const float*)d_in[0];
  const float* norm_g     = (const float*)d_in[1];
  const float* norm_b     = (const float*)d_in[2];
  const float* in_proj_w  = (const float*)d_in[3];
  const float* conv_w     = (const float*)d_in[4];
  const float* conv_b     = (const float*)d_in[5];
  const float* x_proj_w   = (const float*)d_in[6];
  const float* dt_w       = (const float*)d_in[7];
  const float* dt_b       = (const float*)d_in[8];
  const float* A_logs     = (const float*)d_in[9];
  const float* Ds         = (const float*)d_in[10];
  const float* out_norm_g = (const float*)d_in[11];
  const float* out_norm_b = (const float*)d_in[12];
  const float* out_proj_w = (const float*)d_in[13];
  float* out = (float*)d_out;

  float* ws    = (float*)d_ws;
  float* xn    = ws;                   // 1,572,864  (B,L,C)
  float* xz    = xn + 1572864;         // 6,291,456  (B,L,768)
  float* xc    = xz + 6291456;         // 3,145,728  (B,L,DM)
  float* W_all = xc + 3145728;         //    73,728  (384,192)
  float* xdbl  = W_all + 73728;        // 1,572,864  (B,L,192)
  float* dtsS  = xdbl + 1572864;       //   393,216  (BK,L,12) scan-order
  float* BsS   = dtsS + 393216;        //   524,288  (BK,L,16)
  float* CsS   = BsS + 524288;         //   524,288
  float* Pb    = CsS + 524288;         // 6,291,456  (BK,S=128,6144)
  float* Eb    = Pb + 6291456;         // 6,291,456
  float* Hb    = Eb + 6291456;         // 6,291,456
  float* ysum  = Pb;                   // alias: Pb dead after combine (3,145,728 used)
  float* yact  = Eb;                   // alias: Eb dead after combine (3,145,728 used)
  // total: 32,972,800 floats ≈ 131.9 MB

  k_ln<<<dim3(2048), dim3(256), 0, stream>>>(input, norm_g, norm_b, xn);
  k_gemm<0><<<dim3(12, 128), dim3(256), 0, stream>>>(xn, in_proj_w, nullptr, xz, 8192, 768, 192);
  k_conv<<<dim3(8192), dim3(384), 0, stream>>>(xz, conv_w, conv_b, xc);
  k_wpack<<<dim3(288), dim3(256), 0, stream>>>(x_proj_w, W_all);
  k_gemm<0><<<dim3(3, 128), dim3(256), 0, stream>>>(xc, W_all, nullptr, xdbl, 8192, 192, 384);
  k_repack<<<dim3(512), dim3(256), 0, stream>>>(xdbl, dtsS, BsS, CsS);
  k_scan<0><<<dim3(1024), dim3(384), 0, stream>>>(dtsS, BsS, CsS, xc, A_logs, dt_w, dt_b,
                                                  nullptr, Pb, Eb, nullptr);
  k_combine<<<dim3(192), dim3(256), 0, stream>>>(Pb, Eb, Hb);
  hipMemsetAsync(ysum, 0, 3145728 * sizeof(float), stream);
  k_scan<1><<<dim3(1024), dim3(384), 0, stream>>>(dtsS, BsS, CsS, xc, A_logs, dt_w, dt_b,
                                                  Hb, nullptr, nullptr, ysum);
  k_merge<<<dim3(8192), dim3(384), 0, stream>>>(ysum, xc, xz, Ds, out_norm_g, out_norm_b, yact);
  k_gemm<1><<<dim3(3, 128), dim3(256), 0, stream>>>(yact, out_proj_w, input, out, 8192, 192, 384);
}

// Round 4
// 287.401 us; speedup vs baseline: 1.7917x; 1.4801x over previous
//
#include <hip/hip_runtime.h>
#include <hip/hip_bf16.h>

// VSSBlock: B=2 H=64 W=64 C=192 DM=384 N=16 R=12 K=4 L=4096
// R4: all three projections as bf16 MFMA GEMMs (16x16x32, 128x64 tile, fp32 accum).
//     Producers emit bf16 activation copies; weights packed/transposed to bf16 once.
//     Scan path (R3 structure) unchanged and stays fp32.

typedef __attribute__((ext_vector_type(8))) short short8;     // 8 bf16 = 4 VGPRs
typedef __attribute__((ext_vector_type(4))) float floatx4;    // fp32 accum frag

// ---------------- LayerNorm (pre-norm, eps 1e-6), C=192 -> bf16 ----------------
__global__ __launch_bounds__(256) void k_ln(const float* __restrict__ in,
                                            const float* __restrict__ g,
                                            const float* __restrict__ be,
                                            __hip_bfloat16* __restrict__ out) {
  int row = blockIdx.x * 4 + (threadIdx.x >> 6);
  int lane = threadIdx.x & 63;
  const float* x = in + (long)row * 192;
  float v0 = x[lane], v1 = x[lane + 64], v2 = x[lane + 128];
  float s = v0 + v1 + v2;
  float s2 = v0 * v0 + v1 * v1 + v2 * v2;
  #pragma unroll
  for (int o = 32; o > 0; o >>= 1) { s += __shfl_xor(s, o); s2 += __shfl_xor(s2, o); }
  float mu = s * (1.f / 192.f);
  float var = s2 * (1.f / 192.f) - mu * mu;
  float r = rsqrtf(var + 1e-6f);
  __hip_bfloat16* op = out + (long)row * 192;
  op[lane]       = __float2bfloat16((v0 - mu) * r * g[lane]       + be[lane]);
  op[lane + 64]  = __float2bfloat16((v1 - mu) * r * g[lane + 64]  + be[lane + 64]);
  op[lane + 128] = __float2bfloat16((v2 - mu) * r * g[lane + 128] + be[lane + 128]);
}

// ---------------- pack weights -> bf16, transposed to (N x K) ----------------
// Wt1 (768x192) = in_proj_w^T; Wt2 (192x384) = rows of x_proj_w (pad 176..191 = 0);
// Wt3 (192x384) = out_proj_w^T.
__global__ __launch_bounds__(256) void k_packw(const float* __restrict__ ipw,
                                               const float* __restrict__ xpw,
                                               const float* __restrict__ opw,
                                               __hip_bfloat16* __restrict__ Wt1,
                                               __hip_bfloat16* __restrict__ Wt2,
                                               __hip_bfloat16* __restrict__ Wt3) {
  int idx = blockIdx.x * 256 + threadIdx.x;
  if (idx < 147456) {                       // Wt1[n][k] = ipw[k][n]
    int n = idx / 192, k = idx - n * 192;
    Wt1[idx] = __float2bfloat16(ipw[(long)k * 768 + n]);
  } else if (idx < 147456 + 73728) {        // Wt2[j][d]
    int t = idx - 147456;
    int j = t / 384;
    float v = (j < 176) ? xpw[t] : 0.f;
    Wt2[t] = __float2bfloat16(v);
  } else if (idx < 147456 + 73728 + 73728) {// Wt3[n][k] = opw[k][n]
    int t = idx - 147456 - 73728;
    int n = t / 384, k = t - n * 384;
    Wt3[t] = __float2bfloat16(opw[(long)k * 192 + n]);
  }
}

// ---------------- bf16 MFMA GEMM: Co(MxN) = A(MxK) * Bt(NxK)^T [+ Res] ----------------
// 128x64 tile, BK=32, 4 waves in 2x2; wave tile 64x32 = 4x2 frags of 16x16x32.
template <int RES>
__global__ __launch_bounds__(256) void k_gemm_mfma(const __hip_bfloat16* __restrict__ A,
                                                   const __hip_bfloat16* __restrict__ Bt,
                                                   const float* __restrict__ Res,
                                                   float* __restrict__ Co,
                                                   int M, int N, int Kk) {
  __shared__ __align__(16) short As[128 * 32];
  __shared__ __align__(16) short Bs[64 * 32];
  int tid = threadIdx.x;
  int wave = tid >> 6, lane = tid & 63;
  int mlane = lane & 15, quad = lane >> 4;
  int row0 = blockIdx.y * 128, col0 = blockIdx.x * 64;
  int wr = wave & 1, wc = wave >> 1;  // 2x2 wave grid
  floatx4 acc[4][2];
  #pragma unroll
  for (int mi = 0; mi < 4; mi++)
    #pragma unroll
    for (int ni = 0; ni < 2; ni++) acc[mi][ni] = (floatx4){0.f, 0.f, 0.f, 0.f};

  for (int k0 = 0; k0 < Kk; k0 += 32) {
    // stage A-tile: 128 rows x 32 bf16 (64B/row) = 512 chunks of 16B
    #pragma unroll
    for (int c = tid; c < 512; c += 256) {
      int r = c >> 2, off = (c & 3) * 8;
      *(float4*)&As[r * 32 + off] = *(const float4*)&A[(long)(row0 + r) * Kk + k0 + off];
    }
    // stage B-tile: 64 rows x 32 bf16 = 256 chunks
    {
      int c = tid;
      int r = c >> 2, off = (c & 3) * 8;
      *(float4*)&Bs[r * 32 + off] = *(const float4*)&Bt[(long)(col0 + r) * Kk + k0 + off];
    }
    __syncthreads();
    short8 af[4], bf[2];
    #pragma unroll
    for (int mi = 0; mi < 4; mi++)
      af[mi] = *(const short8*)&As[(wr * 64 + mi * 16 + mlane) * 32 + quad * 8];
    #pragma unroll
    for (int ni = 0; ni < 2; ni++)
      bf[ni] = *(const short8*)&Bs[(wc * 32 + ni * 16 + mlane) * 32 + quad * 8];
    #pragma unroll
    for (int mi = 0; mi < 4; mi++)
      #pragma unroll
      for (int ni = 0; ni < 2; ni++)
        acc[mi][ni] = __builtin_amdgcn_mfma_f32_16x16x32_bf16(af[mi], bf[ni], acc[mi][ni], 0, 0, 0);
    __syncthreads();
  }
  // epilogue: C/D layout col=lane&15, row=quad*4+reg  [m89-verified]
  #pragma unroll
  for (int mi = 0; mi < 4; mi++) {
    #pragma unroll
    for (int ni = 0; ni < 2; ni++) {
      int cc = col0 + wc * 32 + ni * 16 + mlane;
      #pragma unroll
      for (int i = 0; i < 4; i++) {
        int rr = row0 + wr * 64 + mi * 16 + quad * 4 + i;
        float v = acc[mi][ni][i];
        if (RES) v += Res[(long)rr * N + cc];
        Co[(long)rr * N + cc] = v;
      }
    }
  }
}

// ---------------- depthwise 3x3 conv + bias + SiLU; writes fp32 xc + bf16 xcb ----------------
__global__ __launch_bounds__(384) void k_conv(const float* __restrict__ xz,
                                              const float* __restrict__ cw,
                                              const float* __restrict__ cb,
                                              float* __restrict__ xc,
                                              __hip_bfloat16* __restrict__ xcb) {
  int row = blockIdx.x;  // b*4096 + p
  int b = row >> 12, p = row & 4095;
  int h = p >> 6, w0 = p & 63;
  int d = threadIdx.x;
  float acc = cb[d];
  const float* wt = cw + d * 9;
  #pragma unroll
  for (int dh = -1; dh <= 1; dh++) {
    int hh = h + dh;
    if (hh < 0 || hh > 63) continue;
    #pragma unroll
    for (int dw = -1; dw <= 1; dw++) {
      int ww = w0 + dw;
      if (ww < 0 || ww > 63) continue;
      acc += xz[((long)(b << 12) + (hh << 6) + ww) * 768 + d] * wt[(dh + 1) * 3 + (dw + 1)];
    }
  }
  float sg = 1.f / (1.f + __expf(-acc));
  float v = acc * sg;
  xc[(long)row * 384 + d] = v;
  xcb[(long)row * 384 + d] = __float2bfloat16(v);
}

// direction mapping: scan position l (direction k) -> pixel index p
__device__ __forceinline__ int dir_pix(int k, int l) {
  if (k == 0) return l;
  if (k == 1) return ((l & 63) << 6) | (l >> 6);
  if (k == 2) return 4095 - l;
  int l2 = 4095 - l;
  return ((l2 & 63) << 6) | (l2 >> 6);
}

// ---------------- repack pixel-major xdbl -> scan-ordered dts/Bs/Cs ----------------
__global__ __launch_bounds__(256) void k_repack(const float* __restrict__ xdbl,
                                                float* __restrict__ dtsS,
                                                float* __restrict__ BsS,
                                                float* __restrict__ CsS) {
  int bid = blockIdx.x;  // bk*64 + lt
  int lt = bid & 63, bk = bid >> 6;
  int k = bk & 3, b = bk >> 2;
  int l0 = lt * 64;
  long bpix = (long)(b << 12);
  int kc = k * 44;
  for (int i = threadIdx.x; i < 64 * 44; i += 256) {
    int t = i / 44, c = i - t * 44;
    int p = dir_pix(k, l0 + t);
    float v = xdbl[(bpix + p) * 192 + kc + c];
    long lbase = (long)bk * 4096 + l0 + t;
    if (c < 12)      dtsS[lbase * 12 + c] = v;
    else if (c < 28) BsS[lbase * 16 + (c - 12)] = v;
    else             CsS[lbase * 16 + (c - 28)] = v;
  }
}

// ---------------- segmented selective scan: 128 segments x 32 steps ----------------
template <int PASS>
__global__ __launch_bounds__(384) void k_scan(
    const float* __restrict__ dtsS, const float* __restrict__ BsS,
    const float* __restrict__ CsS, const float* __restrict__ xc,
    const float* __restrict__ A_logs, const float* __restrict__ dt_w,
    const float* __restrict__ dt_b, const float* __restrict__ Hin,
    float* __restrict__ P, float* __restrict__ E, float* __restrict__ ysum) {
  int bid = blockIdx.x;
  int s = bid & 127, bk = bid >> 7;
  int k = bk & 3, b = bk >> 2;
  int d = threadIdx.x;
  float w[12];
  const float* dwp = dt_w + ((long)(k * 384) + d) * 12;
  #pragma unroll
  for (int r = 0; r < 12; r++) w[r] = dwp[r];
  float db = dt_b[k * 384 + d];
  const float* al = A_logs + ((long)(k * 384) + d) * 16;
  bool pw = true;
  #pragma unroll
  for (int n = 0; n < 16; n++) {
    float a = __expf(al[n]);
    pw = pw && (fabsf(a - (float)(n + 1)) < 1e-3f);
  }
  float h[16];
  if (PASS == 0) {
    #pragma unroll
    for (int n = 0; n < 16; n++) h[n] = 0.f;
  } else {
    const float* hp = Hin + ((long)bk * 128 + s) * 6144 + d * 16;
    #pragma unroll
    for (int n = 0; n < 16; n++) h[n] = hp[n];
  }
  long lb = (long)bk * 4096 + s * 32;
  long bpix = (long)(b << 12);
  float rprod = 1.f;
  float PrG[16];
  #pragma unroll
  for (int n = 0; n < 16; n++) PrG[n] = 1.f;

  if (pw) {
    #pragma unroll 4
    for (int t = 0; t < 32; t++) {
      int l = s * 32 + t;
      const float4* dq = (const float4*)(dtsS + (lb + t) * 12);
      float4 q0 = dq[0], q1 = dq[1], q2 = dq[2];
      float x = db + q0.x * w[0] + q0.y * w[1] + q0.z * w[2] + q0.w * w[3]
                   + q1.x * w[4] + q1.y * w[5] + q1.z * w[6] + q1.w * w[7]
                   + q2.x * w[8] + q2.y * w[9] + q2.z * w[10] + q2.w * w[11];
      float delta = (x > 15.f) ? x : __logf(1.f + __expf(x));
      int p = dir_pix(k, l);
      float u = xc[(bpix + p) * 384 + d];
      float du = delta * u;
      float rr = __expf(-delta);
      const float4* Bq = (const float4*)(BsS + (lb + t) * 16);
      float4 b0 = Bq[0], b1 = Bq[1], b2 = Bq[2], b3 = Bq[3];
      float Bl[16] = {b0.x, b0.y, b0.z, b0.w, b1.x, b1.y, b1.z, b1.w,
                      b2.x, b2.y, b2.z, b2.w, b3.x, b3.y, b3.z, b3.w};
      float rp = rr;
      if (PASS == 0) {
        #pragma unroll
        for (int n = 0; n < 16; n++) { h[n] = rp * h[n] + du * Bl[n]; rp *= rr; }
        rprod *= rr;
      } else {
        const float4* Cq = (const float4*)(CsS + (lb + t) * 16);
        float4 c0 = Cq[0], c1 = Cq[1], c2 = Cq[2], c3 = Cq[3];
        float Cl[16] = {c0.x, c0.y, c0.z, c0.w, c1.x, c1.y, c1.z, c1.w,
                        c2.x, c2.y, c2.z, c2.w, c3.x, c3.y, c3.z, c3.w};
        float y = 0.f;
        #pragma unroll
        for (int n = 0; n < 16; n++) {
          h[n] = rp * h[n] + du * Bl[n];
          y += h[n] * Cl[n];
          rp *= rr;
        }
        atomicAdd(&ysum[(bpix + p) * 384 + d], y);
      }
    }
  } else {
    float av[16];
    #pragma unroll
    for (int n = 0; n < 16; n++) av[n] = -__expf(al[n]);
    for (int t = 0; t < 32; t++) {
      int l = s * 32 + t;
      const float4* dq = (const float4*)(dtsS + (lb + t) * 12);
      float4 q0 = dq[0], q1 = dq[1], q2 = dq[2];
      float x = db + q0.x * w[0] + q0.y * w[1] + q0.z * w[2] + q0.w * w[3]
                   + q1.x * w[4] + q1.y * w[5] + q1.z * w[6] + q1.w * w[7]
                   + q2.x * w[8] + q2.y * w[9] + q2.z * w[10] + q2.w * w[11];
      float delta = (x > 15.f) ? x : __logf(1.f + __expf(x));
      int p = dir_pix(k, l);
      float u = xc[(bpix + p) * 384 + d];
      float du = delta * u;
      const float4* Bq = (const float4*)(BsS + (lb + t) * 16);
      float4 b0 = Bq[0], b1 = Bq[1], b2 = Bq[2], b3 = Bq[3];
      float Bl[16] = {b0.x, b0.y, b0.z, b0.w, b1.x, b1.y, b1.z, b1.w,
                      b2.x, b2.y, b2.z, b2.w, b3.x, b3.y, b3.z, b3.w};
      if (PASS == 0) {
        #pragma unroll
        for (int n = 0; n < 16; n++) {
          float dA = __expf(delta * av[n]);
          h[n] = dA * h[n] + du * Bl[n];
          PrG[n] *= dA;
        }
      } else {
        const float4* Cq = (const float4*)(CsS + (lb + t) * 16);
        float4 c0 = Cq[0], c1 = Cq[1], c2 = Cq[2], c3 = Cq[3];
        float Cl[16] = {c0.x, c0.y, c0.z, c0.w, c1.x, c1.y, c1.z, c1.w,
                        c2.x, c2.y, c2.z, c2.w, c3.x, c3.y, c3.z, c3.w};
        float y = 0.f;
        #pragma unroll
        for (int n = 0; n < 16; n++) {
          float dA = __expf(delta * av[n]);
          h[n] = dA * h[n] + du * Bl[n];
          y += h[n] * Cl[n];
        }
        atomicAdd(&ysum[(bpix + p) * 384 + d], y);
      }
    }
  }
  if (PASS == 0) {
    float* Pp = P + ((long)bk * 128 + s) * 6144 + d * 16;
    float* Ep = E + ((long)bk * 128 + s) * 6144 + d * 16;
    if (pw) {
      float pp = rprod;
      #pragma unroll
      for (int n = 0; n < 16; n++) { Pp[n] = pp; Ep[n] = h[n]; pp *= rprod; }
    } else {
      #pragma unroll
      for (int n = 0; n < 16; n++) { Pp[n] = PrG[n]; Ep[n] = h[n]; }
    }
  }
}

// ---------------- cross-segment combine ----------------
__global__ __launch_bounds__(256) void k_combine(const float* __restrict__ P,
                                                 const float* __restrict__ E,
                                                 float* __restrict__ Hin) {
  int t = blockIdx.x * 256 + threadIdx.x;  // B*K*6144 = 49152
  int bk = t / 6144;
  int dn = t - bk * 6144;
  long base = (long)bk * 128 * 6144 + dn;
  float h = 0.f;
  for (int s = 0; s < 128; s++) {
    long idx = base + (long)s * 6144;
    Hin[idx] = h;
    h = P[idx] * h + E[idx];
  }
}

// ---------------- merge: ysum + D-skip + out-LN + silu(z) gate -> bf16 yact ----------------
__global__ __launch_bounds__(384) void k_merge(const float* __restrict__ ysum,
                                               const float* __restrict__ xc,
                                               const float* __restrict__ xz,
                                               const float* __restrict__ Ds,
                                               const float* __restrict__ g,
                                               const float* __restrict__ be,
                                               __hip_bfloat16* __restrict__ yactb) {
  int row = blockIdx.x;  // b*4096 + p
  int d = threadIdx.x;
  float v = ysum[(long)row * 384 + d];
  float sd = Ds[d] + Ds[384 + d] + Ds[768 + d] + Ds[1152 + d];
  v += xc[(long)row * 384 + d] * sd;
  float s1 = v, s2 = v * v;
  #pragma unroll
  for (int o = 32; o > 0; o >>= 1) { s1 += __shfl_xor(s1, o); s2 += __shfl_xor(s2, o); }
  __shared__ float r1[6], r2[6];
  int wv = threadIdx.x >> 6;
  if ((threadIdx.x & 63) == 0) { r1[wv] = s1; r2[wv] = s2; }
  __syncthreads();
  float S1 = 0.f, S2 = 0.f;
  #pragma unroll
  for (int i = 0; i < 6; i++) { S1 += r1[i]; S2 += r2[i]; }
  float mu = S1 * (1.f / 384.f);
  float var = S2 * (1.f / 384.f) - mu * mu;
  float rr = rsqrtf(var + 1e-5f);
  float yn = (v - mu) * rr * g[d] + be[d];
  float z = xz[(long)row * 768 + 384 + d];
  float sg = z / (1.f + __expf(-z));
  yactb[(long)row * 384 + d] = __float2bfloat16(yn * sg);
}

extern "C" void kernel_launch(void* const* d_in, const int* in_sizes, int n_in,
                              void* d_out, int out_size, void* d_ws, size_t ws_size,
                              hipStream_t stream) {
  const float* input      = (const float*)d_in[0];
  const float* norm_g     = (const float*)d_in[1];
  const float* norm_b     = (const float*)d_in[2];
  const float* in_proj_w  = (const float*)d_in[3];
  const float* conv_w     = (const float*)d_in[4];
  const float* conv_b     = (const float*)d_in[5];
  const float* x_proj_w   = (const float*)d_in[6];
  const float* dt_w       = (const float*)d_in[7];
  const float* dt_b       = (const float*)d_in[8];
  const float* A_logs     = (const float*)d_in[9];
  const float* Ds         = (const float*)d_in[10];
  const float* out_norm_g = (const float*)d_in[11];
  const float* out_norm_b = (const float*)d_in[12];
  const float* out_proj_w = (const float*)d_in[13];
  float* out = (float*)d_out;

  float* ws = (float*)d_ws;
  __hip_bfloat16* xnb  = (__hip_bfloat16*)ws;                    //   786,432 f (8192x192 bf16)
  float* xz    = ws + 786432;          // 6,291,456  (B,L,768)
  float* xc    = xz + 6291456;         // 3,145,728  (B,L,DM) fp32
  __hip_bfloat16* xcb  = (__hip_bfloat16*)(xc + 3145728);        // 1,572,864 f (8192x384 bf16)
  __hip_bfloat16* Wt1  = (__hip_bfloat16*)(xc + 3145728 + 1572864);          //  73,728 f
  __hip_bfloat16* Wt2  = (__hip_bfloat16*)(xc + 3145728 + 1572864 + 73728);  //  36,864 f
  __hip_bfloat16* Wt3  = (__hip_bfloat16*)(xc + 3145728 + 1572864 + 110592); //  36,864 f
  float* xdbl  = xc + 3145728 + 1572864 + 147456;  // 1,572,864  (B,L,192)
  float* dtsS  = xdbl + 1572864;       //   393,216  (BK,L,12) scan-order
  float* BsS   = dtsS + 393216;        //   524,288  (BK,L,16)
  float* CsS   = BsS + 524288;         //   524,288
  float* Pb    = CsS + 524288;         // 6,291,456  (BK,S=128,6144)
  float* Eb    = Pb + 6291456;         // 6,291,456
  float* Hb    = Eb + 6291456;         // 6,291,456
  float* ysum  = Pb;                                  // alias: Pb dead after combine
  __hip_bfloat16* yactb = (__hip_bfloat16*)Eb;        // alias: Eb dead after combine
  // total ≈ 33.8M floats ≈ 135 MB

  k_ln<<<dim3(2048), dim3(256), 0, stream>>>(input, norm_g, norm_b, xnb);
  k_packw<<<dim3(1152), dim3(256), 0, stream>>>(in_proj_w, x_proj_w, out_proj_w, Wt1, Wt2, Wt3);
  // in_proj: (8192x192)@(192x768)
  k_gemm_mfma<0><<<dim3(12, 64), dim3(256), 0, stream>>>(xnb, Wt1, nullptr, xz, 8192, 768, 192);
  k_conv<<<dim3(8192), dim3(384), 0, stream>>>(xz, conv_w, conv_b, xc, xcb);
  // x_proj: (8192x384)@(384x192)
  k_gemm_mfma<0><<<dim3(3, 64), dim3(256), 0, stream>>>(xcb, Wt2, nullptr, xdbl, 8192, 192, 384);
  k_repack<<<dim3(512), dim3(256), 0, stream>>>(xdbl, dtsS, BsS, CsS);
  k_scan<0><<<dim3(1024), dim3(384), 0, stream>>>(dtsS, BsS, CsS, xc, A_logs, dt_w, dt_b,
                                                  nullptr, Pb, Eb, nullptr);
  k_combine<<<dim3(192), dim3(256), 0, stream>>>(Pb, Eb, Hb);
  hipMemsetAsync(ysum, 0, 3145728 * sizeof(float), stream);
  k_scan<1><<<dim3(1024), dim3(384), 0, stream>>>(dtsS, BsS, CsS, xc, A_logs, dt_w, dt_b,
                                                  Hb, nullptr, nullptr, ysum);
  k_merge<<<dim3(8192), dim3(384), 0, stream>>>(ysum, xc, xz, Ds, out_norm_g, out_norm_b, yactb);
  // out_proj + residual: (8192x384)@(384x192) + input
  k_gemm_mfma<1><<<dim3(3, 64), dim3(256), 0, stream>>>(yactb, Wt3, input, out, 8192, 192, 384);
}